// Round 2
// baseline (322.704 us; speedup 1.0000x reference)
//
#include <hip/hip_runtime.h>

#define EMBED 768
#define POOL  32
#define PLEN  32
#define TOPK  5
#define NCLS  1000

// prompts row = 77*768 = 59136 floats = 14784 float4
//   token 0      : prefix    (192 f4)
//   tokens 1..32 : combined  (32 * 192 f4)
//   tokens 33..64: ctx       (32 * 192 f4)
//   tokens 65..76: suffix    (12 * 192 f4)
#define ROW_F4     14784
#define TOK_F4     192          // 768 floats per token = 192 float4
#define PRE_F4     192
#define SUF_F4     2304         // 12*192

#define PROMPTS_F4 14784000     // 1000 * ROW_F4
#define POOL_F4    196608       // 32*32*768/4
#define KEY_F4     6144         // 32*768/4
#define PASS_F4    (POOL_F4 + KEY_F4)   // 202752 = 792*256

#define RPB 8                   // rows (classes) per block in the row writer

// native clang vector type — accepted by __builtin_nontemporal_{load,store}
typedef float vf4 __attribute__((ext_vector_type(4)));

// ---------------- kernel 1: fused top-5 + gated sum -> combined [32,768] ---
// 32 blocks (one per token position); each block redundantly recomputes the
// top-5 selection (reads are tiny and L2-hot), avoiding a separate launch.
__global__ __launch_bounds__(256) void selgate_kernel(
    const float* __restrict__ x_embed,   // [16,768]
    const float* __restrict__ key,       // [32,768]
    const float* __restrict__ pool,      // [32,32,768]
    const float* __restrict__ alpha_w,   // [768]
    const float* __restrict__ alpha_b,   // [1]
    float* __restrict__ combined)        // [32,768]
{
    __shared__ float qs[EMBED];
    __shared__ float sim[POOL];
    __shared__ int   idx[TOPK];
    __shared__ float wsh[TOPK];

    int l = blockIdx.x;    // token position 0..31
    int t = threadIdx.x;

    // q = sum over 16 frames (mean/norm scaling is rank-irrelevant for top-k)
    if (t < TOK_F4) {
        const vf4* x4 = (const vf4*)x_embed;
        vf4 s = 0.f;
        #pragma unroll
        for (int f = 0; f < 16; ++f) s += x4[f * TOK_F4 + t];
        ((vf4*)qs)[t] = s;
    }
    __syncthreads();

    // 8 lanes per pool entry: dot(key_p, q) and ||key_p||, vectorized vf4
    {
        int p = t >> 3, j = t & 7;
        const vf4* k4 = (const vf4*)(key + p * EMBED);
        const vf4* q4 = (const vf4*)qs;
        float dot = 0.f, nrm = 0.f;
        for (int d = j; d < TOK_F4; d += 8) {
            vf4 kv = k4[d];
            vf4 qv = q4[d];
            dot += kv.x * qv.x + kv.y * qv.y + kv.z * qv.z + kv.w * qv.w;
            nrm += kv.x * kv.x + kv.y * kv.y + kv.z * kv.z + kv.w * kv.w;
        }
        #pragma unroll
        for (int off = 4; off >= 1; off >>= 1) {
            dot += __shfl_down(dot, off, 8);
            nrm += __shfl_down(nrm, off, 8);
        }
        if (j == 0) sim[p] = dot * rsqrtf(nrm);
    }
    __syncthreads();

    if (t == 0) {
        unsigned used = 0;
        for (int k = 0; k < TOPK; ++k) {
            float best = -1e30f; int bi = 0;
            for (int q = 0; q < POOL; ++q) {
                if (used & (1u << q)) continue;
                if (sim[q] > best) { best = sim[q]; bi = q; }
            }
            used |= 1u << bi;
            idx[k] = bi;
        }
    }
    __syncthreads();

    // per-token sigmoid gates: one wave per k (wave 0 also takes k=4),
    // full-wave shuffle reduce — replaces 5 serial LDS-tree reductions.
    {
        int wave = t >> 6, lane = t & 63;
        for (int k = wave; k < TOPK; k += 4) {
            const float* row = pool + ((size_t)idx[k] * PLEN + l) * EMBED;
            float s = 0.f;
            for (int d = lane; d < EMBED; d += 64) s += row[d] * alpha_w[d];
            #pragma unroll
            for (int off = 32; off >= 1; off >>= 1) s += __shfl_down(s, off);
            if (lane == 0) wsh[k] = 1.f / (1.f + __expf(-(s + alpha_b[0])));
        }
    }
    __syncthreads();

    for (int d = t; d < EMBED; d += 256) {
        float s = 0.f;
        #pragma unroll
        for (int k = 0; k < TOPK; ++k)
            s += wsh[k] * pool[((size_t)idx[k] * PLEN + l) * EMBED + d];
        combined[l * EMBED + d] = s;
    }
}

// ---------------- kernel 2: row writer, 2D grid, no div, uniform branch ----
// grid = (77 tokens, 1000/RPB row-chunks), block = 192 threads (1 f4/thread).
// Segment selection is block-uniform (token index = blockIdx.x); broadcast
// tokens (combined/ctx) load once and store to RPB rows; output stores are
// nontemporal (out is never re-read -> avoid write-allocate RFO traffic).
__global__ __launch_bounds__(192) void row_write_kernel(
    const vf4* __restrict__ prefix,    // [1000,192]
    const vf4* __restrict__ suffix,    // [1000,2304]
    const vf4* __restrict__ ctx,       // [6144]
    const vf4* __restrict__ combined,  // [6144]
    vf4* __restrict__ out)
{
    int j  = blockIdx.x;          // token 0..76
    int r0 = blockIdx.y * RPB;    // first class row of this block
    int t  = threadIdx.x;         // 0..191

    if (j >= 1 && j < 65) {
        // broadcast region: one cached load, RPB streaming stores
        vf4 v = (j < 33) ? combined[(j - 1) * TOK_F4 + t]
                         : ctx[(j - 33) * TOK_F4 + t];
        size_t base = (size_t)r0 * ROW_F4 + (size_t)j * TOK_F4 + t;
        #pragma unroll
        for (int i = 0; i < RPB; ++i)
            __builtin_nontemporal_store(v, &out[base + (size_t)i * ROW_F4]);
    } else if (j == 0) {
        #pragma unroll
        for (int i = 0; i < RPB; ++i) {
            vf4 v = __builtin_nontemporal_load(
                &prefix[(size_t)(r0 + i) * PRE_F4 + t]);
            __builtin_nontemporal_store(v, &out[(size_t)(r0 + i) * ROW_F4 + t]);
        }
    } else {
        int so = (j - 65) * TOK_F4 + t;
        size_t base = (size_t)r0 * ROW_F4 + (size_t)j * TOK_F4 + t;
        #pragma unroll
        for (int i = 0; i < RPB; ++i) {
            vf4 v = __builtin_nontemporal_load(
                &suffix[(size_t)(r0 + i) * SUF_F4 + so]);
            __builtin_nontemporal_store(v, &out[base + (size_t)i * ROW_F4]);
        }
    }
}

// ---------------- kernel 3: pool/key pass-through ---------------------------
__global__ __launch_bounds__(256) void copy_kernel(
    const vf4* __restrict__ pool4,    // [196608]
    const vf4* __restrict__ key4,     // [6144]
    vf4* __restrict__ out)            // out + PROMPTS_F4
{
    unsigned g = blockIdx.x * 256u + threadIdx.x;   // < PASS_F4
    vf4 v = (g < POOL_F4) ? __builtin_nontemporal_load(&pool4[g])
                          : __builtin_nontemporal_load(&key4[g - POOL_F4]);
    __builtin_nontemporal_store(v, &out[PROMPTS_F4 + g]);
}

extern "C" void kernel_launch(void* const* d_in, const int* in_sizes, int n_in,
                              void* d_out, int out_size, void* d_ws, size_t ws_size,
                              hipStream_t stream) {
    const float* x_embed  = (const float*)d_in[0];
    const float* pool     = (const float*)d_in[1];
    const float* key      = (const float*)d_in[2];
    const float* alpha_w  = (const float*)d_in[3];
    const float* alpha_b  = (const float*)d_in[4];
    const float* ctx      = (const float*)d_in[5];
    const float* prefix   = (const float*)d_in[6];
    const float* suffix   = (const float*)d_in[7];
    float* out = (float*)d_out;

    float* combined_ws = (float*)d_ws;   // 32*768 floats

    selgate_kernel<<<PLEN, 256, 0, stream>>>(x_embed, key, pool, alpha_w,
                                             alpha_b, combined_ws);

    row_write_kernel<<<dim3(77, NCLS / RPB), 192, 0, stream>>>(
        (const vf4*)prefix, (const vf4*)suffix,
        (const vf4*)ctx, (const vf4*)combined_ws,
        (vf4*)out);

    copy_kernel<<<PASS_F4 / 256, 256, 0, stream>>>(
        (const vf4*)pool, (const vf4*)key, (vf4*)out);
}

// Round 3
// 319.516 us; speedup vs baseline: 1.0100x; 1.0100x over previous
//
#include <hip/hip_runtime.h>

#define EMBED 768
#define POOL  32
#define PLEN  32
#define TOPK  5
#define NCLS  1000

// prompts row = 77*768 = 59136 floats = 14784 float4
//   token 0      : prefix    (192 f4)
//   tokens 1..32 : combined  (32 * 192 f4)
//   tokens 33..64: ctx       (32 * 192 f4)
//   tokens 65..76: suffix    (12 * 192 f4)
#define ROW_F4     14784
#define TOK_F4     192          // 768 floats per token = 192 float4
#define PRE_F4     192
#define SUF_F4     2304         // 12*192

#define PROMPTS_F4 14784000     // 1000 * ROW_F4
#define POOL_F4    196608       // 32*32*768/4
#define KEY_F4     6144         // 32*768/4
#define PASS_F4    (POOL_F4 + KEY_F4)   // 202752

#define RPB 10                  // rows (classes) per block in the row writer
#define NY  (NCLS / RPB)        // 100
#define PASS_XCOLS 2            // blockIdx.x in {77,78} handle pass-through
#define PASS_BLKS  (PASS_XCOLS * NY)        // 200
#define PASS_PER_T 6            // 200 blk * 192 thr * 6 f4 = 230400 >= 202752

// native clang vector type — accepted by __builtin_nontemporal_{load,store}
typedef float vf4 __attribute__((ext_vector_type(4)));

// ---------------- kernel 1: fused top-5 + gated sum -> combined [32,768] ---
// 32 blocks (one per token position); each block redundantly recomputes the
// top-5 selection (reads are tiny and L2-hot). Verified exact (absmax=0).
__global__ __launch_bounds__(256) void selgate_kernel(
    const float* __restrict__ x_embed,   // [16,768]
    const float* __restrict__ key,       // [32,768]
    const float* __restrict__ pool,      // [32,32,768]
    const float* __restrict__ alpha_w,   // [768]
    const float* __restrict__ alpha_b,   // [1]
    float* __restrict__ combined)        // [32,768]
{
    __shared__ float qs[EMBED];
    __shared__ float sim[POOL];
    __shared__ int   idx[TOPK];
    __shared__ float wsh[TOPK];

    int l = blockIdx.x;    // token position 0..31
    int t = threadIdx.x;

    // q = sum over 16 frames (mean/norm scaling is rank-irrelevant for top-k)
    if (t < TOK_F4) {
        const vf4* x4 = (const vf4*)x_embed;
        vf4 s = 0.f;
        #pragma unroll
        for (int f = 0; f < 16; ++f) s += x4[f * TOK_F4 + t];
        ((vf4*)qs)[t] = s;
    }
    __syncthreads();

    // 8 lanes per pool entry: dot(key_p, q) and ||key_p||, vectorized vf4
    {
        int p = t >> 3, j = t & 7;
        const vf4* k4 = (const vf4*)(key + p * EMBED);
        const vf4* q4 = (const vf4*)qs;
        float dot = 0.f, nrm = 0.f;
        for (int d = j; d < TOK_F4; d += 8) {
            vf4 kv = k4[d];
            vf4 qv = q4[d];
            dot += kv.x * qv.x + kv.y * qv.y + kv.z * qv.z + kv.w * qv.w;
            nrm += kv.x * kv.x + kv.y * kv.y + kv.z * kv.z + kv.w * kv.w;
        }
        #pragma unroll
        for (int off = 4; off >= 1; off >>= 1) {
            dot += __shfl_down(dot, off, 8);
            nrm += __shfl_down(nrm, off, 8);
        }
        if (j == 0) sim[p] = dot * rsqrtf(nrm);
    }
    __syncthreads();

    if (t == 0) {
        unsigned used = 0;
        for (int k = 0; k < TOPK; ++k) {
            float best = -1e30f; int bi = 0;
            for (int q = 0; q < POOL; ++q) {
                if (used & (1u << q)) continue;
                if (sim[q] > best) { best = sim[q]; bi = q; }
            }
            used |= 1u << bi;
            idx[k] = bi;
        }
    }
    __syncthreads();

    // per-token sigmoid gates: one wave per k (wave 0 also takes k=4)
    {
        int wave = t >> 6, lane = t & 63;
        for (int k = wave; k < TOPK; k += 4) {
            const float* row = pool + ((size_t)idx[k] * PLEN + l) * EMBED;
            float s = 0.f;
            for (int d = lane; d < EMBED; d += 64) s += row[d] * alpha_w[d];
            #pragma unroll
            for (int off = 32; off >= 1; off >>= 1) s += __shfl_down(s, off);
            if (lane == 0) wsh[k] = 1.f / (1.f + __expf(-(s + alpha_b[0])));
        }
    }
    __syncthreads();

    for (int d = t; d < EMBED; d += 256) {
        float s = 0.f;
        #pragma unroll
        for (int k = 0; k < TOPK; ++k)
            s += wsh[k] * pool[((size_t)idx[k] * PLEN + l) * EMBED + d];
        combined[l * EMBED + d] = s;
    }
}

// ---------------- kernel 2: mega writer ------------------------------------
// grid = (77 + 2, 100), block = 192 threads.
//   x < 77 : prompts token x for RPB=10 class rows (uniform branch per block;
//            broadcast tokens load once, store RPB times; nt stores avoid
//            polluting L2 with the 236 MB output stream)
//   x >= 77: pool/key pass-through (200 blocks * 192 thr * 6 f4)
__global__ __launch_bounds__(192) void mega_write_kernel(
    const vf4* __restrict__ prefix,    // [1000,192]
    const vf4* __restrict__ suffix,    // [1000,2304]
    const vf4* __restrict__ ctx,       // [6144]
    const vf4* __restrict__ combined,  // [6144]
    const vf4* __restrict__ pool4,     // [196608]
    const vf4* __restrict__ key4,      // [6144]
    vf4* __restrict__ out)
{
    int j = blockIdx.x;           // token 0..76, or 77/78 for pass-through
    int y = blockIdx.y;           // 0..99
    int t = threadIdx.x;          // 0..191

    if (j >= 77) {
        // pass-through: pool then key appended after prompts
        int pid = (j - 77) * NY + y;                 // 0..199
        unsigned base = (unsigned)pid * (PASS_PER_T * 192) + t;
        #pragma unroll
        for (int i = 0; i < PASS_PER_T; ++i) {
            unsigned g = base + i * 192;
            if (g < PASS_F4) {
                vf4 v = (g < POOL_F4)
                    ? __builtin_nontemporal_load(&pool4[g])
                    : __builtin_nontemporal_load(&key4[g - POOL_F4]);
                __builtin_nontemporal_store(v, &out[PROMPTS_F4 + g]);
            }
        }
        return;
    }

    int r0 = y * RPB;             // first class row of this block

    if (j >= 1 && j < 65) {
        // broadcast region: one cached load, RPB streaming stores
        vf4 v = (j < 33) ? combined[(j - 1) * TOK_F4 + t]
                         : ctx[(j - 33) * TOK_F4 + t];
        size_t base = (size_t)r0 * ROW_F4 + (size_t)j * TOK_F4 + t;
        #pragma unroll
        for (int i = 0; i < RPB; ++i)
            __builtin_nontemporal_store(v, &out[base + (size_t)i * ROW_F4]);
    } else if (j == 0) {
        #pragma unroll
        for (int i = 0; i < RPB; ++i) {
            vf4 v = __builtin_nontemporal_load(
                &prefix[(size_t)(r0 + i) * PRE_F4 + t]);
            __builtin_nontemporal_store(v, &out[(size_t)(r0 + i) * ROW_F4 + t]);
        }
    } else {
        int so = (j - 65) * TOK_F4 + t;
        size_t base = (size_t)r0 * ROW_F4 + (size_t)j * TOK_F4 + t;
        #pragma unroll
        for (int i = 0; i < RPB; ++i) {
            vf4 v = __builtin_nontemporal_load(
                &suffix[(size_t)(r0 + i) * SUF_F4 + so]);
            __builtin_nontemporal_store(v, &out[base + (size_t)i * ROW_F4]);
        }
    }
}

extern "C" void kernel_launch(void* const* d_in, const int* in_sizes, int n_in,
                              void* d_out, int out_size, void* d_ws, size_t ws_size,
                              hipStream_t stream) {
    const float* x_embed  = (const float*)d_in[0];
    const float* pool     = (const float*)d_in[1];
    const float* key      = (const float*)d_in[2];
    const float* alpha_w  = (const float*)d_in[3];
    const float* alpha_b  = (const float*)d_in[4];
    const float* ctx      = (const float*)d_in[5];
    const float* prefix   = (const float*)d_in[6];
    const float* suffix   = (const float*)d_in[7];
    float* out = (float*)d_out;

    float* combined_ws = (float*)d_ws;   // 32*768 floats

    selgate_kernel<<<PLEN, 256, 0, stream>>>(x_embed, key, pool, alpha_w,
                                             alpha_b, combined_ws);

    mega_write_kernel<<<dim3(77 + PASS_XCOLS, NY), 192, 0, stream>>>(
        (const vf4*)prefix, (const vf4*)suffix,
        (const vf4*)ctx, (const vf4*)combined_ws,
        (const vf4*)pool, (const vf4*)key,
        (vf4*)out);
}